// Round 17
// baseline (354.208 us; speedup 1.0000x reference)
//
#include <hip/hip_runtime.h>

#define SEQ   512
#define BATCH 64
#define HID   1024
#define NX    8
#define SG    8      // s-groups per batch (attention); 64 rows each
#define SB    8      // rows per register batch
#define NBAT  8      // 8*8 = 64 rows per attn block
#define YBB   2      // batches per y_kernel block

// ---------------------------------------------------------------------------
// step1_init_kernel: ONE launch doing step-1 y GEMV (blocks 0..1023) plus all
// one-time prep (blocks 1024..2335). t=1 needs only WK, so init (WC/WVT/bc)
// runs concurrently with it.
//   bid <1024        : y[b,n] = sum_h q[b,h]*WK[h,n]   (nc=bid&31 -> XCD=nc%8)
//   bid <1280 (+1024): wc_gemm 64x64 tile  WC = WV^T . WK
//   bid <2304        : transpose tile      WVT[h][n] = WV[n][h]
//   bid <2336        : bc slice            bc[n] = sum_j bV[j]*WK[j,n]
// ---------------------------------------------------------------------------
__global__ __launch_bounds__(256) void step1_init_kernel(
    const float* __restrict__ WV, const float* __restrict__ WK,
    const float* __restrict__ bV, const float* __restrict__ q,
    float* __restrict__ WVT, float* __restrict__ WC,
    float* __restrict__ bc, float* __restrict__ y)
{
    __shared__ float smem[2 * 32 * 68];   // 17.4 KB union
    const int bid = blockIdx.x;
    const int tid = threadIdx.x;

    if (bid < 1024) {
        // ---- y (t==1, x=q, W=WK), r16 y_kernel mode-0 body, YBB=2 ----
        float* xs  = smem;                 // [h][bl], 2048 floats
        float* red = smem + 2048;          // [jg][nl][bl], 512 floats
        const int nc = bid & 31, bg = bid >> 5;
        const int b0 = bg * YBB;

        for (int h = tid; h < HID; h += 256) {
            #pragma unroll
            for (int bl = 0; bl < YBB; bl++)
                xs[h * YBB + bl] = q[(size_t)(b0 + bl) * HID + h];
        }
        __syncthreads();

        const int nl = tid & 31, jg = tid >> 5;
        const int n = nc * 32 + nl;
        const float* __restrict__ wp = WK + (size_t)(jg * 128) * HID + n;
        const float* __restrict__ xr = xs + jg * 128 * YBB;
        float accx = 0.f, accy = 0.f;
        #pragma unroll 8
        for (int jj = 0; jj < 128; jj++) {
            const float wv = wp[(size_t)jj * HID];
            const float2 x2 = *(const float2*)(xr + jj * YBB);
            accx += x2.x * wv; accy += x2.y * wv;
        }
        red[(jg * 32 + nl) * YBB + 0] = accx;
        red[(jg * 32 + nl) * YBB + 1] = accy;
        __syncthreads();
        if (tid < 32 * YBB) {
            const int nl2 = tid & 31, bl = tid >> 5;
            float s = 0.f;
            #pragma unroll
            for (int g = 0; g < 8; g++) s += red[(g * 32 + nl2) * YBB + bl];
            y[(size_t)(b0 + bl) * HID + nc * 32 + nl2] = s;
        }
    } else if (bid < 1280) {
        // ---- wc_gemm: 64x64 tile, 4x4 acc/thread, reg-dbuf staging ----
        float (*As)[68] = (float(*)[68])smem;
        float (*Bs)[68] = (float(*)[68])(smem + 32 * 68);
        const int idx = bid - 1024;
        const int nt = idx & 15, mt = idx >> 4;
        const int nx = tid & 15, my = tid >> 4;
        const int r = tid >> 3, c = (tid & 7) * 8;

        float acc[4][4] = {};
        float4 a0 = *(const float4*)(WV + (size_t)r * HID + mt * 64 + c);
        float4 a1 = *(const float4*)(WV + (size_t)r * HID + mt * 64 + c + 4);
        float4 b0 = *(const float4*)(WK + (size_t)r * HID + nt * 64 + c);
        float4 b1 = *(const float4*)(WK + (size_t)r * HID + nt * 64 + c + 4);

        for (int k0 = 0; k0 < HID; k0 += 32) {
            *(float4*)&As[r][c]     = a0;
            *(float4*)&As[r][c + 4] = a1;
            *(float4*)&Bs[r][c]     = b0;
            *(float4*)&Bs[r][c + 4] = b1;
            __syncthreads();
            if (k0 + 32 < HID) {
                a0 = *(const float4*)(WV + (size_t)(k0 + 32 + r) * HID + mt * 64 + c);
                a1 = *(const float4*)(WV + (size_t)(k0 + 32 + r) * HID + mt * 64 + c + 4);
                b0 = *(const float4*)(WK + (size_t)(k0 + 32 + r) * HID + nt * 64 + c);
                b1 = *(const float4*)(WK + (size_t)(k0 + 32 + r) * HID + nt * 64 + c + 4);
            }
            #pragma unroll 8
            for (int kk = 0; kk < 32; kk++) {
                const float4 a = *(const float4*)&As[kk][my * 4];
                const float4 b = *(const float4*)&Bs[kk][nx * 4];
                acc[0][0] += a.x * b.x; acc[0][1] += a.x * b.y;
                acc[0][2] += a.x * b.z; acc[0][3] += a.x * b.w;
                acc[1][0] += a.y * b.x; acc[1][1] += a.y * b.y;
                acc[1][2] += a.y * b.z; acc[1][3] += a.y * b.w;
                acc[2][0] += a.z * b.x; acc[2][1] += a.z * b.y;
                acc[2][2] += a.z * b.z; acc[2][3] += a.z * b.w;
                acc[3][0] += a.w * b.x; acc[3][1] += a.w * b.y;
                acc[3][2] += a.w * b.z; acc[3][3] += a.w * b.w;
            }
            __syncthreads();
        }
        const int m = mt * 64 + my * 4, n = nt * 64 + nx * 4;
        #pragma unroll
        for (int i = 0; i < 4; i++)
            *(float4*)(WC + (size_t)(m + i) * HID + n) = *(float4*)acc[i];
    } else if (bid < 2304) {
        // ---- transpose tile ----
        float (*tile)[33] = (float(*)[33])smem;
        const int idx = bid - 1280;
        const int bx = (idx & 31) * 32, by = (idx >> 5) * 32;
        const int tx = tid & 31, ty = tid >> 5;
        #pragma unroll
        for (int r2 = ty; r2 < 32; r2 += 8)
            tile[r2][tx] = WV[(size_t)(by + r2) * HID + bx + tx];
        __syncthreads();
        #pragma unroll
        for (int r2 = ty; r2 < 32; r2 += 8)
            WVT[(size_t)(bx + r2) * HID + by + tx] = tile[tx][r2];
    } else {
        // ---- bc slice ----
        float* xs  = smem;           // 1024
        float* red = smem + 1024;    // 8*32
        const int nc = bid - 2304;
        *(float4*)(xs + tid * 4) = *(const float4*)(bV + tid * 4);
        __syncthreads();
        const int nl = tid & 31, jg = tid >> 5;
        const int n = nc * 32 + nl;
        const float* __restrict__ wp = WK + (size_t)(jg * 128) * HID + n;
        const float* __restrict__ xr = xs + jg * 128;
        float acc = 0.f;
        #pragma unroll 8
        for (int jj = 0; jj < 128; jj++)
            acc += xr[jj] * wp[(size_t)jj * HID];
        red[jg * 32 + nl] = acc;
        __syncthreads();
        if (tid < 32) {
            float s = 0.f;
            #pragma unroll
            for (int g = 0; g < 8; g++) s += red[g * 32 + tid];
            bc[nc * 32 + tid] = s;
        }
    }
}

// ---------------------------------------------------------------------------
// y_kernel (t>=2 only): y[b,n] = sum_h z[b,h]*WC[h,n] + bc[n]; YBB batches
// per block; x = rescale(zp, ml); nc==0 writes zs_slot.
// grid (nc=32, bg=32), nc FASTEST (XCD = nc%8 keeps W chunks L2-resident).
// ---------------------------------------------------------------------------
__global__ __launch_bounds__(256) void y_kernel(
    const float* __restrict__ W, const float* __restrict__ zp,
    const float* __restrict__ ml, const float* __restrict__ bc,
    float* __restrict__ zs_slot, float* __restrict__ y)
{
    __shared__ float xs[HID * YBB];        // [h][bl], 8 KiB
    __shared__ float red[8][32][YBB];      // 2 KiB
    const int nc = blockIdx.x, bg = blockIdx.y;
    const int b0 = bg * YBB;
    const int tid = threadIdx.x;

    float es[YBB][SG], invL[YBB];
    #pragma unroll
    for (int bl = 0; bl < YBB; bl++) {
        const int b = b0 + bl;
        float M = -1e30f;
        #pragma unroll
        for (int g = 0; g < SG; g++) M = fmaxf(M, ml[b * 2 * SG + 2 * g]);
        float L = 0.f;
        #pragma unroll
        for (int g = 0; g < SG; g++) {
            es[bl][g] = __expf(ml[b * 2 * SG + 2 * g] - M);
            L += ml[b * 2 * SG + 2 * g + 1] * es[bl][g];
        }
        invL[bl] = 1.0f / L;
    }
    for (int h = tid; h < HID; h += 256) {
        #pragma unroll
        for (int bl = 0; bl < YBB; bl++) {
            const int b = b0 + bl;
            float s = 0.f;
            #pragma unroll
            for (int g = 0; g < SG; g++)
                s += zp[((size_t)(b * SG + g)) * HID + h] * es[bl][g];
            s *= invL[bl];
            xs[h * YBB + bl] = s;
            if (nc == 0 && zs_slot) zs_slot[(size_t)b * HID + h] = s;
        }
    }
    __syncthreads();

    const int nl = tid & 31, jg = tid >> 5;
    const int n = nc * 32 + nl;
    const float* __restrict__ wp = W + (size_t)(jg * 128) * HID + n;
    const float* __restrict__ xr = xs + jg * 128 * YBB;
    float accx = 0.f, accy = 0.f;
    #pragma unroll 8
    for (int jj = 0; jj < 128; jj++) {
        const float wv = wp[(size_t)jj * HID];
        const float2 x2 = *(const float2*)(xr + jj * YBB);
        accx += x2.x * wv; accy += x2.y * wv;
    }
    red[jg][nl][0] = accx;
    red[jg][nl][1] = accy;
    __syncthreads();
    if (tid < 32 * YBB) {
        const int nl2 = tid & 31, bl = tid >> 5;
        float s = 0.f;
        #pragma unroll
        for (int g = 0; g < 8; g++) s += red[g][nl2][bl];
        s += bc[nc * 32 + nl2];
        y[(size_t)(b0 + bl) * HID + nc * 32 + nl2] = s;
    }
}

// ---------------------------------------------------------------------------
// fused_attn: grid (sg=8, b=64). 64 rows/block, online (m,l) flash; hidden
// rows in registers. Writes zp[b,sg,:] (unnormalized) and ml[b,sg]=(m,l).
// ---------------------------------------------------------------------------
__global__ __launch_bounds__(256) void fused_attn_kernel(
    const float* __restrict__ hidden, const float* __restrict__ y,
    float* __restrict__ zp, float* __restrict__ ml)
{
    const int sg = blockIdx.x, b = blockIdx.y;
    const int tid = threadIdx.x;
    const int lane = tid & 63, w = tid >> 6;
    const int h4 = tid * 4;

    __shared__ float part[4][SB];

    const float4 yv = *(const float4*)(y + (size_t)b * HID + h4);
    float m = -1e30f, l = 0.f;
    float4 acc = {0.f, 0.f, 0.f, 0.f};

    for (int bb = 0; bb < NBAT; bb++) {
        float4 hv[SB];
        float p[SB];
        #pragma unroll
        for (int r = 0; r < SB; r++) {
            const int s = sg * 64 + bb * SB + r;
            hv[r] = *(const float4*)(hidden + ((size_t)s * BATCH + b) * HID + h4);
            p[r] = hv[r].x * yv.x + hv[r].y * yv.y
                 + hv[r].z * yv.z + hv[r].w * yv.w;
        }
        #pragma unroll
        for (int r = 0; r < SB; r++) {
            float s = p[r];
            #pragma unroll
            for (int off = 32; off; off >>= 1) s += __shfl_xor(s, off);
            if (lane == 0) part[w][r] = s;
        }
        __syncthreads();
        float sc[SB], mb = -1e30f;
        #pragma unroll
        for (int r = 0; r < SB; r++) {
            sc[r] = part[0][r] + part[1][r] + part[2][r] + part[3][r];
            mb = fmaxf(mb, sc[r]);
        }
        __syncthreads();
        const float newm  = fmaxf(m, mb);
        const float scale = __expf(m - newm);
        l *= scale;
        acc.x *= scale; acc.y *= scale; acc.z *= scale; acc.w *= scale;
        #pragma unroll
        for (int r = 0; r < SB; r++) {
            const float we = __expf(sc[r] - newm);
            l += we;
            acc.x += we * hv[r].x; acc.y += we * hv[r].y;
            acc.z += we * hv[r].z; acc.w += we * hv[r].w;
        }
        m = newm;
    }
    *(float4*)(zp + ((size_t)(b * SG + sg)) * HID + h4) = acc;
    if (tid == 0) {
        ml[(b * SG + sg) * 2 + 0] = m;
        ml[(b * SG + sg) * 2 + 1] = l;
    }
}

// ---------------------------------------------------------------------------
// final_gemm: out rows 1..7; row 0 = q.  grid (nc=32, b=64) — nc fastest.
// ---------------------------------------------------------------------------
__global__ __launch_bounds__(256) void final_gemm(
    const float* __restrict__ WVT, const float* __restrict__ zs,
    const float* __restrict__ zp, const float* __restrict__ ml,
    const float* __restrict__ q, const float* __restrict__ bV,
    float* __restrict__ out)
{
    __shared__ float zst[7][HID];     // 28 KiB
    __shared__ float red[8][7][32];   // 7 KiB
    const int nc = blockIdx.x, b = blockIdx.y;
    const int tid = threadIdx.x;

    float M = -1e30f;
    #pragma unroll
    for (int g = 0; g < SG; g++) M = fmaxf(M, ml[b * 2 * SG + 2 * g]);
    float es[SG], L = 0.f;
    #pragma unroll
    for (int g = 0; g < SG; g++) {
        es[g] = __expf(ml[b * 2 * SG + 2 * g] - M);
        L += ml[b * 2 * SG + 2 * g + 1] * es[g];
    }
    const float invL = 1.0f / L;

    for (int i = tid; i < 7 * HID; i += 256) {
        const int si = i >> 10;
        const int h  = i & (HID - 1);
        float v;
        if (si < 6) {
            v = zs[((size_t)si * BATCH + b) * HID + h];
        } else {
            v = 0.f;
            #pragma unroll
            for (int g = 0; g < SG; g++)
                v += zp[((size_t)(b * SG + g)) * HID + h] * es[g];
            v *= invL;
        }
        zst[si][h] = v;
    }
    __syncthreads();

    const int nl = tid & 31, hg = tid >> 5;
    const int n = nc * 32 + nl;
    const float* __restrict__ wp = WVT + (size_t)(hg * 128) * HID + n;
    float acc[7] = {};
    #pragma unroll 4
    for (int hh = 0; hh < 128; hh++) {
        const float wv = wp[(size_t)hh * HID];
        const int h = hg * 128 + hh;
        #pragma unroll
        for (int si = 0; si < 7; si++)
            acc[si] += zst[si][h] * wv;
    }
    #pragma unroll
    for (int si = 0; si < 7; si++) red[hg][si][nl] = acc[si];
    __syncthreads();

    if (tid < 224) {
        const int si = tid >> 5, nl2 = tid & 31;
        const int n2 = nc * 32 + nl2;
        float s = bV[n2];
        #pragma unroll
        for (int g = 0; g < 8; g++) s += red[g][si][nl2];
        out[((size_t)(b * NX + si + 1)) * HID + n2] = s;
    } else {
        const int nl2 = tid - 224;
        const int n2 = nc * 32 + nl2;
        out[((size_t)(b * NX)) * HID + n2] = q[(size_t)b * HID + n2];
    }
}

// ---------------------------------------------------------------------------
extern "C" void kernel_launch(void* const* d_in, const int* in_sizes, int n_in,
                              void* d_out, int out_size, void* d_ws, size_t ws_size,
                              hipStream_t stream)
{
    const float* hidden = (const float*)d_in[1];
    const float* q      = (const float*)d_in[2];
    const float* WK     = (const float*)d_in[3];
    const float* WV     = (const float*)d_in[5];
    const float* bV     = (const float*)d_in[6];
    float* out = (float*)d_out;

    char* ws = (char*)d_ws;
    float* WVT = (float*)(ws);                               // 4 MiB
    float* WC  = (float*)(ws + (4  << 20));                  // 4 MiB
    float* zp  = (float*)(ws + (8  << 20));                  // 2 MiB
    float* zs  = (float*)(ws + (10 << 20));                  // 6 slots, 1.5 MiB
    float* y   = (float*)(ws + (12 << 20));                  // 256 KiB
    float* ml  = (float*)(ws + (12 << 20) + (256 << 10));    // 4 KiB
    float* bc  = (float*)(ws + (12 << 20) + (512 << 10));    // 4 KiB

    // t=1 y GEMV + all one-time init in a single launch
    step1_init_kernel<<<2336, 256, 0, stream>>>(
        WV, WK, bV, q, WVT, WC, bc, y);
    fused_attn_kernel<<<dim3(SG, BATCH), 256, 0, stream>>>(
        hidden, y, zp, ml);

    for (int t = 2; t < NX; t++) {
        float* slot = zs + (size_t)(t - 2) * BATCH * HID;
        y_kernel<<<dim3(32, BATCH / YBB), 256, 0, stream>>>(
            WC, zp, ml, bc, slot, y);
        fused_attn_kernel<<<dim3(SG, BATCH), 256, 0, stream>>>(
            hidden, y, zp, ml);
    }
    final_gemm<<<dim3(32, BATCH), 256, 0, stream>>>(
        WVT, zs, zp, ml, q, bV, out);
}

// Round 18
// 332.202 us; speedup vs baseline: 1.0662x; 1.0662x over previous
//
#include <hip/hip_runtime.h>

#define SEQ   512
#define BATCH 64
#define HID   1024
#define NX    8
#define SG    8      // s-groups per batch (attention); 64 rows each
#define SB    8      // rows per register batch
#define NBAT  8      // 8*8 = 64 rows per attn block
#define YBB   2      // batches per y_kernel block

// ---------------------------------------------------------------------------
// init_kernel: one-time prep, K-split wc for parallelism.
//   bid <1024 : wc partial: WCp[ks][m,n] = sum_{j in ks-slice} WV[j,m]*WK[j,n]
//               (ks = bid>>8, 64x64 tile, K=256 per slice)
//   bid <2048 : transpose tile  WVT[h][n] = WV[n][h]
//   bid <2080 : bc slice        bc[n] = sum_j bV[j]*WK[j,n]
// ---------------------------------------------------------------------------
__global__ __launch_bounds__(256) void init_kernel(
    const float* __restrict__ WV, const float* __restrict__ WK,
    const float* __restrict__ bV, float* __restrict__ WVT,
    float* __restrict__ WCp, float* __restrict__ bc)
{
    __shared__ float smem[2 * 32 * 68];   // 17.4 KB union
    const int bid = blockIdx.x;
    const int tid = threadIdx.x;

    if (bid < 1024) {
        // ---- wc partial: 64x64 tile, 4x4 acc/thread, K slice of 256 ----
        float (*As)[68] = (float(*)[68])smem;
        float (*Bs)[68] = (float(*)[68])(smem + 32 * 68);
        const int ks  = bid >> 8;
        const int idx = bid & 255;
        const int nt = idx & 15, mt = idx >> 4;
        const int nx = tid & 15, my = tid >> 4;
        const int r = tid >> 3, c = (tid & 7) * 8;
        const int kbase = ks * 256;

        float acc[4][4] = {};
        float4 a0 = *(const float4*)(WV + (size_t)(kbase + r) * HID + mt * 64 + c);
        float4 a1 = *(const float4*)(WV + (size_t)(kbase + r) * HID + mt * 64 + c + 4);
        float4 b0 = *(const float4*)(WK + (size_t)(kbase + r) * HID + nt * 64 + c);
        float4 b1 = *(const float4*)(WK + (size_t)(kbase + r) * HID + nt * 64 + c + 4);

        for (int k0 = kbase; k0 < kbase + 256; k0 += 32) {
            *(float4*)&As[r][c]     = a0;
            *(float4*)&As[r][c + 4] = a1;
            *(float4*)&Bs[r][c]     = b0;
            *(float4*)&Bs[r][c + 4] = b1;
            __syncthreads();
            if (k0 + 32 < kbase + 256) {
                a0 = *(const float4*)(WV + (size_t)(k0 + 32 + r) * HID + mt * 64 + c);
                a1 = *(const float4*)(WV + (size_t)(k0 + 32 + r) * HID + mt * 64 + c + 4);
                b0 = *(const float4*)(WK + (size_t)(k0 + 32 + r) * HID + nt * 64 + c);
                b1 = *(const float4*)(WK + (size_t)(k0 + 32 + r) * HID + nt * 64 + c + 4);
            }
            #pragma unroll 8
            for (int kk = 0; kk < 32; kk++) {
                const float4 a = *(const float4*)&As[kk][my * 4];
                const float4 b = *(const float4*)&Bs[kk][nx * 4];
                acc[0][0] += a.x * b.x; acc[0][1] += a.x * b.y;
                acc[0][2] += a.x * b.z; acc[0][3] += a.x * b.w;
                acc[1][0] += a.y * b.x; acc[1][1] += a.y * b.y;
                acc[1][2] += a.y * b.z; acc[1][3] += a.y * b.w;
                acc[2][0] += a.z * b.x; acc[2][1] += a.z * b.y;
                acc[2][2] += a.z * b.z; acc[2][3] += a.z * b.w;
                acc[3][0] += a.w * b.x; acc[3][1] += a.w * b.y;
                acc[3][2] += a.w * b.z; acc[3][3] += a.w * b.w;
            }
            __syncthreads();
        }
        float* dst = WCp + (size_t)ks * HID * HID;
        const int m = mt * 64 + my * 4, n = nt * 64 + nx * 4;
        #pragma unroll
        for (int i = 0; i < 4; i++)
            *(float4*)(dst + (size_t)(m + i) * HID + n) = *(float4*)acc[i];
    } else if (bid < 2048) {
        // ---- transpose tile ----
        float (*tile)[33] = (float(*)[33])smem;
        const int idx = bid - 1024;
        const int bx = (idx & 31) * 32, by = (idx >> 5) * 32;
        const int tx = tid & 31, ty = tid >> 5;
        #pragma unroll
        for (int r2 = ty; r2 < 32; r2 += 8)
            tile[r2][tx] = WV[(size_t)(by + r2) * HID + bx + tx];
        __syncthreads();
        #pragma unroll
        for (int r2 = ty; r2 < 32; r2 += 8)
            WVT[(size_t)(bx + r2) * HID + by + tx] = tile[tx][r2];
    } else {
        // ---- bc slice: nc = bid - 2048 ----
        float* xs  = smem;           // 1024
        float* red = smem + 1024;    // 8*32
        const int nc = bid - 2048;
        *(float4*)(xs + tid * 4) = *(const float4*)(bV + tid * 4);
        __syncthreads();
        const int nl = tid & 31, jg = tid >> 5;
        const int n = nc * 32 + nl;
        const float* __restrict__ wp = WK + (size_t)(jg * 128) * HID + n;
        const float* __restrict__ xr = xs + jg * 128;
        float acc = 0.f;
        #pragma unroll 8
        for (int jj = 0; jj < 128; jj++)
            acc += xr[jj] * wp[(size_t)jj * HID];
        red[jg * 32 + nl] = acc;
        __syncthreads();
        if (tid < 32) {
            float s = 0.f;
            #pragma unroll
            for (int g = 0; g < 8; g++) s += red[g * 32 + tid];
            bc[nc * 32 + tid] = s;
        }
    }
}

// ---------------------------------------------------------------------------
// wcadd: WC = WCp[0] + WCp[1] + WCp[2] + WCp[3]   (1M floats, float4)
// ---------------------------------------------------------------------------
__global__ __launch_bounds__(256) void wcadd_kernel(
    const float* __restrict__ WCp, float* __restrict__ WC)
{
    const size_t i = ((size_t)blockIdx.x * 256 + threadIdx.x) * 4;
    const size_t S = (size_t)HID * HID;
    float4 a = *(const float4*)(WCp + i);
    float4 b = *(const float4*)(WCp + S + i);
    float4 c = *(const float4*)(WCp + 2 * S + i);
    float4 d = *(const float4*)(WCp + 3 * S + i);
    float4 o;
    o.x = (a.x + b.x) + (c.x + d.x);
    o.y = (a.y + b.y) + (c.y + d.y);
    o.z = (a.z + b.z) + (c.z + d.z);
    o.w = (a.w + b.w) + (c.w + d.w);
    *(float4*)(WC + i) = o;
}

// ---------------------------------------------------------------------------
// y_kernel: y[b,n] = sum_h x[b,h] * W[h,n] (+ bc[n]); YBB batches per block.
// grid (nc=32, bg=32), nc FASTEST -> XCD = nc%8 keeps each XCD's 4 W chunks
// (512KB) L2-resident (r14/r15-validated).
// mode 0 (t==1): x = q, W = WK, no bc.
// mode 1 (t>=2): x = rescale(zp, ml), W = WC, + bc; nc==0 writes zs_slot.
// ---------------------------------------------------------------------------
__global__ __launch_bounds__(256) void y_kernel(
    const float* __restrict__ W, const float* __restrict__ q,
    const float* __restrict__ zp, const float* __restrict__ ml,
    const float* __restrict__ bc, float* __restrict__ zs_slot,
    float* __restrict__ y, int mode)
{
    __shared__ float xs[HID * YBB];        // [h][bl], 8 KiB
    __shared__ float red[8][32][YBB];      // 2 KiB
    const int nc = blockIdx.x, bg = blockIdx.y;
    const int b0 = bg * YBB;
    const int tid = threadIdx.x;

    if (mode == 0) {
        for (int h = tid; h < HID; h += 256) {
            #pragma unroll
            for (int bl = 0; bl < YBB; bl++)
                xs[h * YBB + bl] = q[(size_t)(b0 + bl) * HID + h];
        }
    } else {
        float es[YBB][SG], invL[YBB];
        #pragma unroll
        for (int bl = 0; bl < YBB; bl++) {
            const int b = b0 + bl;
            float M = -1e30f;
            #pragma unroll
            for (int g = 0; g < SG; g++) M = fmaxf(M, ml[b * 2 * SG + 2 * g]);
            float L = 0.f;
            #pragma unroll
            for (int g = 0; g < SG; g++) {
                es[bl][g] = __expf(ml[b * 2 * SG + 2 * g] - M);
                L += ml[b * 2 * SG + 2 * g + 1] * es[bl][g];
            }
            invL[bl] = 1.0f / L;
        }
        for (int h = tid; h < HID; h += 256) {
            #pragma unroll
            for (int bl = 0; bl < YBB; bl++) {
                const int b = b0 + bl;
                float s = 0.f;
                #pragma unroll
                for (int g = 0; g < SG; g++)
                    s += zp[((size_t)(b * SG + g)) * HID + h] * es[bl][g];
                s *= invL[bl];
                xs[h * YBB + bl] = s;
                if (nc == 0 && zs_slot) zs_slot[(size_t)b * HID + h] = s;
            }
        }
    }
    __syncthreads();

    const int nl = tid & 31, jg = tid >> 5;
    const int n = nc * 32 + nl;
    const float* __restrict__ wp = W + (size_t)(jg * 128) * HID + n;
    const float* __restrict__ xr = xs + jg * 128 * YBB;
    float accx = 0.f, accy = 0.f;
    #pragma unroll 8
    for (int jj = 0; jj < 128; jj++) {
        const float wv = wp[(size_t)jj * HID];
        const float2 x2 = *(const float2*)(xr + jj * YBB);
        accx += x2.x * wv; accy += x2.y * wv;
    }
    red[jg][nl][0] = accx;
    red[jg][nl][1] = accy;
    __syncthreads();
    if (tid < 32 * YBB) {
        const int nl2 = tid & 31, bl = tid >> 5;
        float s = 0.f;
        #pragma unroll
        for (int g = 0; g < 8; g++) s += red[g][nl2][bl];
        if (mode != 0) s += bc[nc * 32 + nl2];
        y[(size_t)(b0 + bl) * HID + nc * 32 + nl2] = s;
    }
}

// ---------------------------------------------------------------------------
// fused_attn: grid (sg=8, b=64). 64 rows/block, online (m,l) flash; hidden
// rows in registers. Writes zp[b,sg,:] (unnormalized) and ml[b,sg]=(m,l).
// ---------------------------------------------------------------------------
__global__ __launch_bounds__(256) void fused_attn_kernel(
    const float* __restrict__ hidden, const float* __restrict__ y,
    float* __restrict__ zp, float* __restrict__ ml)
{
    const int sg = blockIdx.x, b = blockIdx.y;
    const int tid = threadIdx.x;
    const int lane = tid & 63, w = tid >> 6;
    const int h4 = tid * 4;

    __shared__ float part[4][SB];

    const float4 yv = *(const float4*)(y + (size_t)b * HID + h4);
    float m = -1e30f, l = 0.f;
    float4 acc = {0.f, 0.f, 0.f, 0.f};

    for (int bb = 0; bb < NBAT; bb++) {
        float4 hv[SB];
        float p[SB];
        #pragma unroll
        for (int r = 0; r < SB; r++) {
            const int s = sg * 64 + bb * SB + r;
            hv[r] = *(const float4*)(hidden + ((size_t)s * BATCH + b) * HID + h4);
            p[r] = hv[r].x * yv.x + hv[r].y * yv.y
                 + hv[r].z * yv.z + hv[r].w * yv.w;
        }
        #pragma unroll
        for (int r = 0; r < SB; r++) {
            float s = p[r];
            #pragma unroll
            for (int off = 32; off; off >>= 1) s += __shfl_xor(s, off);
            if (lane == 0) part[w][r] = s;
        }
        __syncthreads();
        float sc[SB], mb = -1e30f;
        #pragma unroll
        for (int r = 0; r < SB; r++) {
            sc[r] = part[0][r] + part[1][r] + part[2][r] + part[3][r];
            mb = fmaxf(mb, sc[r]);
        }
        __syncthreads();
        const float newm  = fmaxf(m, mb);
        const float scale = __expf(m - newm);
        l *= scale;
        acc.x *= scale; acc.y *= scale; acc.z *= scale; acc.w *= scale;
        #pragma unroll
        for (int r = 0; r < SB; r++) {
            const float we = __expf(sc[r] - newm);
            l += we;
            acc.x += we * hv[r].x; acc.y += we * hv[r].y;
            acc.z += we * hv[r].z; acc.w += we * hv[r].w;
        }
        m = newm;
    }
    *(float4*)(zp + ((size_t)(b * SG + sg)) * HID + h4) = acc;
    if (tid == 0) {
        ml[(b * SG + sg) * 2 + 0] = m;
        ml[(b * SG + sg) * 2 + 1] = l;
    }
}

// ---------------------------------------------------------------------------
// final_gemm: out rows 1..7; row 0 = q.  grid (nc=32, b=64) — nc fastest.
// ---------------------------------------------------------------------------
__global__ __launch_bounds__(256) void final_gemm(
    const float* __restrict__ WVT, const float* __restrict__ zs,
    const float* __restrict__ zp, const float* __restrict__ ml,
    const float* __restrict__ q, const float* __restrict__ bV,
    float* __restrict__ out)
{
    __shared__ float zst[7][HID];     // 28 KiB
    __shared__ float red[8][7][32];   // 7 KiB
    const int nc = blockIdx.x, b = blockIdx.y;
    const int tid = threadIdx.x;

    float M = -1e30f;
    #pragma unroll
    for (int g = 0; g < SG; g++) M = fmaxf(M, ml[b * 2 * SG + 2 * g]);
    float es[SG], L = 0.f;
    #pragma unroll
    for (int g = 0; g < SG; g++) {
        es[g] = __expf(ml[b * 2 * SG + 2 * g] - M);
        L += ml[b * 2 * SG + 2 * g + 1] * es[g];
    }
    const float invL = 1.0f / L;

    for (int i = tid; i < 7 * HID; i += 256) {
        const int si = i >> 10;
        const int h  = i & (HID - 1);
        float v;
        if (si < 6) {
            v = zs[((size_t)si * BATCH + b) * HID + h];
        } else {
            v = 0.f;
            #pragma unroll
            for (int g = 0; g < SG; g++)
                v += zp[((size_t)(b * SG + g)) * HID + h] * es[g];
            v *= invL;
        }
        zst[si][h] = v;
    }
    __syncthreads();

    const int nl = tid & 31, hg = tid >> 5;
    const int n = nc * 32 + nl;
    const float* __restrict__ wp = WVT + (size_t)(hg * 128) * HID + n;
    float acc[7] = {};
    #pragma unroll 4
    for (int hh = 0; hh < 128; hh++) {
        const float wv = wp[(size_t)hh * HID];
        const int h = hg * 128 + hh;
        #pragma unroll
        for (int si = 0; si < 7; si++)
            acc[si] += zst[si][h] * wv;
    }
    #pragma unroll
    for (int si = 0; si < 7; si++) red[hg][si][nl] = acc[si];
    __syncthreads();

    if (tid < 224) {
        const int si = tid >> 5, nl2 = tid & 31;
        const int n2 = nc * 32 + nl2;
        float s = bV[n2];
        #pragma unroll
        for (int g = 0; g < 8; g++) s += red[g][si][nl2];
        out[((size_t)(b * NX + si + 1)) * HID + n2] = s;
    } else {
        const int nl2 = tid - 224;
        const int n2 = nc * 32 + nl2;
        out[((size_t)(b * NX)) * HID + n2] = q[(size_t)b * HID + n2];
    }
}

// ---------------------------------------------------------------------------
extern "C" void kernel_launch(void* const* d_in, const int* in_sizes, int n_in,
                              void* d_out, int out_size, void* d_ws, size_t ws_size,
                              hipStream_t stream)
{
    const float* hidden = (const float*)d_in[1];
    const float* q      = (const float*)d_in[2];
    const float* WK     = (const float*)d_in[3];
    const float* WV     = (const float*)d_in[5];
    const float* bV     = (const float*)d_in[6];
    float* out = (float*)d_out;

    char* ws = (char*)d_ws;
    float* WVT = (float*)(ws);                               // 4 MiB
    float* WC  = (float*)(ws + (4  << 20));                  // 4 MiB
    float* zp  = (float*)(ws + (8  << 20));                  // 2 MiB
    float* zs  = (float*)(ws + (10 << 20));                  // 6 slots, 1.5 MiB
    float* y   = (float*)(ws + (12 << 20));                  // 256 KiB
    float* ml  = (float*)(ws + (12 << 20) + (256 << 10));    // 4 KiB
    float* bc  = (float*)(ws + (12 << 20) + (512 << 10));    // 4 KiB
    float* WCp = (float*)(ws + (16 << 20));                  // 16 MiB (4 slices)

    init_kernel<<<2080, 256, 0, stream>>>(WV, WK, bV, WVT, WCp, bc);
    wcadd_kernel<<<(HID * HID) / (256 * 4), 256, 0, stream>>>(WCp, WC);

    for (int t = 1; t < NX; t++) {
        if (t == 1) {
            y_kernel<<<dim3(32, BATCH / YBB), 256, 0, stream>>>(
                WK, q, nullptr, nullptr, nullptr, nullptr, y, 0);
        } else {
            float* slot = zs + (size_t)(t - 2) * BATCH * HID;
            y_kernel<<<dim3(32, BATCH / YBB), 256, 0, stream>>>(
                WC, nullptr, zp, ml, bc, slot, y, 1);
        }
        fused_attn_kernel<<<dim3(SG, BATCH), 256, 0, stream>>>(
            hidden, y, zp, ml);
    }
    final_gemm<<<dim3(32, BATCH), 256, 0, stream>>>(
        WVT, zs, zp, ml, q, bV, out);
}